// Round 10
// baseline (224.437 us; speedup 1.0000x reference)
//
#include <hip/hip_runtime.h>
#include <math.h>

#define B_ 2
#define H_ 16
#define S_ 2048
#define D_ 72
#define LP 576
#define WEND 1088
#define DP 96        // padded D for qn/kn (3 chunks of 32)
#define DV 80        // padded dims for Vt (5 tiles of 16)
#define NQ (S_ - LP) // 1472 valid q rows

// attn LDS layout (32-bit words): double-buffered 32-key tiles
#define KS 52                    // K row stride (48 w + 4 pad; 52%32=20, mult of 4)
#define VS 20                    // Vt row stride (16 w + 4 pad)
#define PW 20                    // P row stride (16 w + 4 pad)
#define KBUF 1664                // 32*52
#define VBUF 1600                // 80*20
#define K0B 0
#define K1B KBUF                 // 1664
#define V0B (2*KBUF)             // 3328
#define V1B (2*KBUF + VBUF)      // 4928
#define PBASE (2*KBUF + 2*VBUF)  // 6528
#define LDSW (PBASE + 4*16*PW)   // 7808 words = 31232 B

#define NPREP2 (B_ * H_ * S_ / 8)   // 8192 blocks, 8 rows each (2 rows/wave)
#define NVT    (32 * B_ * H_)       // 1024 blocks

typedef __bf16 bf16x8 __attribute__((ext_vector_type(8)));
typedef float f32x4 __attribute__((ext_vector_type(4)));

static __device__ __forceinline__ unsigned pack2bf(float a, float b) {
    __bf16 x = (__bf16)a, y = (__bf16)b;
    unsigned short ux = __builtin_bit_cast(unsigned short, x);
    unsigned short uy = __builtin_bit_cast(unsigned short, y);
    return (unsigned)ux | ((unsigned)uy << 16);
}

static __device__ __forceinline__ f32x4 mfma16(bf16x8 a, bf16x8 b, f32x4 c) {
    return __builtin_amdgcn_mfma_f32_16x16x32_bf16(a, b, c, 0, 0, 0);
}

// ---------- fused pre: prep (2 rows/wave, LDS-repacked uint4 stores) | vtrans (+zero) ----------
__global__ __launch_bounds__(256) void pre_kernel(
    const float* __restrict__ q, const float* __restrict__ k,
    const float* __restrict__ v,
    const float* __restrict__ pos, const float* __restrict__ pos_orig,
    const float* __restrict__ time_, const float* __restrict__ freqs,
    const float* __restrict__ t_freqs, const float* __restrict__ scale,
    unsigned* __restrict__ qn, unsigned* __restrict__ kn,
    unsigned short* __restrict__ vt, float* __restrict__ out)
{
    __shared__ __align__(16) float tile[64 * 77];  // vtrans; aliased by prep repack
    if (blockIdx.x < NPREP2) {
        unsigned short* shp = (unsigned short*)tile;  // [2][8][96] ushorts
        const int wave = threadIdx.x >> 6;
        const int lane = threadIdx.x & 63;
        const int j = lane & 31;               // lane within row
        const int rw = wave * 2 + (lane >> 5); // row within block (0..7)
        const int row = blockIdx.x * 8 + rw;
        const int s = row & (S_ - 1);
        const int h = (row >> 11) & (H_ - 1);
        const int b = row >> 15;
        const long base = (long)row * D_;
        const int p2 = (b * S_ + s) * 2;

        float oq1 = 0.f, oq2 = 0.f, ok1 = 0.f, ok2 = 0.f;
        float pq[6], pk[6];
        float ssq = 0.f, ssk = 0.f;
        if (j < 30) {
            const float x1q = q[base + j], x2q = q[base + j + 30];
            const float x1k = k[base + j], x2k = k[base + j + 30];
            const int g = j / 6, i = j - 6 * g;
            const float fh = freqs[96 + h * 6 + i];
            const float fw = freqs[h * 6 + i];
            const float ft = t_freqs[h * 6 + i];
            const float f  = (g < 2) ? fh : ((g < 4) ? fw : ft);
            const float by_o = pos_orig[p2 + 1] * 2.f - 1.f;
            const float by_p = pos[p2 + 1]      * 2.f - 1.f;
            const float bx_o = pos_orig[p2 + 0] * 2.f - 1.f;
            const float bx_p = pos[p2 + 0]      * 2.f - 1.f;
            const float bt   = time_[b * S_ + s];
            const float bv = (g == 0) ? by_o : (g == 1) ? by_p :
                             (g == 2) ? bx_o : (g == 3) ? bx_p : bt;
            float sn, cs;
            __sincosf(bv * f, &sn, &cs);
            oq1 = x1q * cs - x2q * sn;  oq2 = x2q * cs + x1q * sn;
            ok1 = x1k * cs - x2k * sn;  ok2 = x2k * cs + x1k * sn;
            ssq = oq1 * oq1 + oq2 * oq2;
            ssk = ok1 * ok1 + ok2 * ok2;
        } else {
            const int e0 = 60 + 6 * (j - 30);
            #pragma unroll
            for (int m = 0; m < 3; ++m) {
                const float2 a = *(const float2*)(q + base + e0 + 2 * m);
                const float2 c = *(const float2*)(k + base + e0 + 2 * m);
                pq[2 * m] = a.x; pq[2 * m + 1] = a.y;
                pk[2 * m] = c.x; pk[2 * m + 1] = c.y;
                ssq += a.x * a.x + a.y * a.y;
                ssk += c.x * c.x + c.y * c.y;
            }
        }
        #pragma unroll
        for (int m = 1; m < 32; m <<= 1) { ssq += __shfl_xor(ssq, m); ssk += __shfl_xor(ssk, m); }
        const float ss = sqrtf(scale[h]);
        const float fq = ss * rsqrtf(ssq + 1e-6f);
        const float fk = ss * rsqrtf(ssk + 1e-6f);

        unsigned short* sq_ = shp + rw * 96;          // [8][96] q
        unsigned short* sk_ = shp + 768 + rw * 96;    // k
        if (j < 30) {
            sq_[j]      = __builtin_bit_cast(unsigned short, (__bf16)(oq1 * fq));
            sq_[j + 30] = __builtin_bit_cast(unsigned short, (__bf16)(oq2 * fq));
            sk_[j]      = __builtin_bit_cast(unsigned short, (__bf16)(ok1 * fk));
            sk_[j + 30] = __builtin_bit_cast(unsigned short, (__bf16)(ok2 * fk));
        } else {
            const int e0 = 60 + 6 * (j - 30);
            #pragma unroll
            for (int m = 0; m < 6; ++m) {
                sq_[e0 + m] = __builtin_bit_cast(unsigned short, (__bf16)(pq[m] * fq));
                sk_[e0 + m] = __builtin_bit_cast(unsigned short, (__bf16)(pk[m] * fk));
            }
        }
        __syncthreads();
        // repack: 2 arrays x 8 rows x 12 uint4 = 192 coalesced stores
        const int t = threadIdx.x;
        if (t < 192) {
            const int arr = t / 96, rem = t - arr * 96;
            const int rr = rem / 12, seg = rem - rr * 12;
            uint4 val = make_uint4(0u, 0u, 0u, 0u);
            if (seg < 9) val = ((const uint4*)(shp + arr * 768 + rr * 96))[seg];
            unsigned* dst = (arr ? kn : qn) + ((long)(blockIdx.x * 8 + rr)) * 48;
            ((uint4*)dst)[seg] = val;
        }
    } else {
        // ---- vtrans (+ zero of out rows < LP) ----
        const int bx2 = blockIdx.x - NPREP2;
        const int st = bx2 & 31, bh = bx2 >> 5;
        const int s0 = st * 64;
        const int t = threadIdx.x;
        if (st < 9) {
            float4* o4 = (float4*)(out + (long)(bh * S_ + s0) * D_);
            for (int i = t; i < 1152; i += 256) o4[i] = make_float4(0.f, 0.f, 0.f, 0.f);
        }
        for (int i = t; i < 1152; i += 256) {
            const int r = i / 18, c = i - r * 18;
            const float4 g = ((const float4*)v)[((long)(bh * S_ + s0 + r) * 18) + c];
            float* d = &tile[r * 77 + c * 4];
            d[0] = g.x; d[1] = g.y; d[2] = g.z; d[3] = g.w;
        }
        __syncthreads();
        for (int i = t; i < 1280; i += 256) {
            const int dd = i >> 4, s4 = i & 15;
            float f0 = 0.f, f1 = 0.f, f2 = 0.f, f3 = 0.f;
            if (dd < D_) {
                f0 = tile[(s4 * 4 + 0) * 77 + dd];
                f1 = tile[(s4 * 4 + 1) * 77 + dd];
                f2 = tile[(s4 * 4 + 2) * 77 + dd];
                f3 = tile[(s4 * 4 + 3) * 77 + dd];
            }
            uint2 o; o.x = pack2bf(f0, f1); o.y = pack2bf(f2, f3);
            ((uint2*)vt)[((((long)bh * DV + dd) << 11) + s0 + s4 * 4) >> 2] = o;
        }
    }
}

// ---------- attention: 4 waves x 16 q-rows, 32-key double-buffered LDS tiles ----------
// Register-staged prefetch: global loads for tile t+1 issued before computing tile t;
// ds_write after compute -> vmcnt wait overlaps compute. One barrier per tile.
__global__ __launch_bounds__(256) void attn_kernel(
    const unsigned short* __restrict__ qn, const unsigned short* __restrict__ kn,
    const unsigned short* __restrict__ vt, float* __restrict__ out)
{
    __shared__ __align__(16) unsigned lds[LDSW];
    const int bh = blockIdx.y;
    const int q0 = LP + blockIdx.x * 64;
    const int tid = threadIdx.x;
    const int w = tid >> 6, lane = tid & 63;
    const int quad = lane >> 4, l16 = lane & 15;
    const int q0w = q0 + 16 * w;
    const bool causal = (q0 < WEND);
    const int ntiles = causal ? ((q0 + 63) >> 5) + 1 : (WEND >> 5);

    const unsigned short* qn_b = qn + (((long)bh) << 11) * DP;
    const unsigned short* kn_b = kn + (((long)bh) << 11) * DP;
    const unsigned short* vt_b = vt + (long)bh * DV * S_;

    bf16x8 qf[3];
    #pragma unroll
    for (int c = 0; c < 3; ++c)
        qf[c] = *(const bf16x8*)(qn_b + (long)(q0w + l16) * DP + c * 32 + quad * 8);

    f32x4 o[5];
    float den[4];
    #pragma unroll
    for (int dt = 0; dt < 5; ++dt) { o[dt][0]=0.f; o[dt][1]=0.f; o[dt][2]=0.f; o[dt][3]=0.f; }
    #pragma unroll
    for (int r = 0; r < 4; ++r) den[r] = 0.f;

    unsigned* Ps = lds + PBASE + w * (16 * PW);

    // staging role of this thread (fixed): 3 slots
    uint4 pf[3];

    auto loadT = [&](int kt) {
        const int k0 = kt * 32;
        #pragma unroll
        for (int ii = 0; ii < 3; ++ii) {
            const int i = tid + ii * 256;
            if (i < 384) {
                const int r = i / 12, seg = i - r * 12;
                const int key = k0 + 2 * (r & 15) + (r >> 4);
                pf[ii] = *(const uint4*)(kn_b + (long)key * DP + seg * 8);
            } else if (i < 704) {
                const int j = i - 384;
                const int rr = j >> 2, seg = j & 3;
                pf[ii] = *(const uint4*)(vt_b + (((long)rr) << 11) + k0 + seg * 8);
            }
        }
    };
    auto writeT = [&](int b) {
        const int kb = b ? K1B : K0B;
        const int vb = b ? V1B : V0B;
        #pragma unroll
        for (int ii = 0; ii < 3; ++ii) {
            const int i = tid + ii * 256;
            if (i < 384) {
                const int r = i / 12, seg = i - r * 12;
                *(uint4*)(lds + kb + r * KS + seg * 4) = pf[ii];
            } else if (i < 704) {
                const int j = i - 384;
                const int rr = j >> 2, seg = j & 3;
                *(uint4*)(lds + vb + rr * VS + seg * 4) = pf[ii];
            }
        }
    };

    loadT(0);
    writeT(0);
    __syncthreads();

    for (int kt = 0; kt < ntiles; ++kt) {
        const int p = kt & 1;
        const bool hasNext = (kt + 1 < ntiles);
        if (hasNext) loadT(kt + 1);   // in flight across compute

        const int kbase = p ? K1B : K0B;
        const int vbase = p ? V1B : V0B;
        const int k0 = kt * 32;

        // QK: G=0 even keys, G=1 odd keys
        f32x4 acc[2];
        #pragma unroll
        for (int G = 0; G < 2; ++G) { acc[G][0]=0.f; acc[G][1]=0.f; acc[G][2]=0.f; acc[G][3]=0.f; }
        #pragma unroll
        for (int c = 0; c < 3; ++c)
            #pragma unroll
            for (int G = 0; G < 2; ++G) {
                const bf16x8 kf = *(const bf16x8*)(lds + kbase + (16 * G + l16) * KS + c * 16 + quad * 4);
                acc[G] = mfma16(qf[c], kf, acc[G]);
            }
        // exp + pack P
        const int kb2 = k0 + 2 * l16;
        #pragma unroll
        for (int r = 0; r < 4; ++r) {
            const int qa = q0w + quad * 4 + r;
            float p0 = acc[0][r], p1 = acc[1][r];
            p0 = (!causal || kb2     <= qa) ? __expf(p0) : 0.f;
            p1 = (!causal || kb2 + 1 <= qa) ? __expf(p1) : 0.f;
            const __bf16 pb0 = (__bf16)p0, pb1 = (__bf16)p1;
            den[r] += (float)pb0 + (float)pb1;
            Ps[(quad * 4 + r) * PW + l16] =
                (unsigned)__builtin_bit_cast(unsigned short, pb0) |
                ((unsigned)__builtin_bit_cast(unsigned short, pb1) << 16);
        }
        // PV: P round-trip (per-wave region; same-wave LDS ordering)
        const bf16x8 pa = *(const bf16x8*)(Ps + l16 * PW + quad * 4);
        #pragma unroll
        for (int dt = 0; dt < 5; ++dt) {
            const bf16x8 vf = *(const bf16x8*)(lds + vbase + (dt * 16 + l16) * VS + quad * 4);
            o[dt] = mfma16(pa, vf, o[dt]);
        }

        if (hasNext) writeT(1 - p);   // vmcnt wait lands here, after compute
        __syncthreads();
    }

    #pragma unroll
    for (int r = 0; r < 4; ++r)
        #pragma unroll
        for (int x = 1; x < 16; x <<= 1) den[r] += __shfl_xor(den[r], x);

    if (!causal) {  // diagonal self-key k == q (window rows)
        float* PsD = (float*)Ps;
        float sp = 0.f;
        #pragma unroll
        for (int c = 0; c < 3; ++c) {
            const bf16x8 kd = *(const bf16x8*)(kn_b + (long)(q0w + l16) * DP + c * 32 + quad * 8);
            #pragma unroll
            for (int j = 0; j < 8; ++j) sp += (float)qf[c][j] * (float)kd[j];
        }
        sp += __shfl_xor(sp, 16);
        sp += __shfl_xor(sp, 32);
        if (quad == 0) PsD[l16] = __expf(sp);
        #pragma unroll
        for (int r = 0; r < 4; ++r) {
            const float pd = PsD[quad * 4 + r];
            den[r] += pd;
            const int qa = q0w + quad * 4 + r;
            #pragma unroll
            for (int dt = 0; dt < 5; ++dt) {
                const unsigned short uv = vt_b[(((long)(dt * 16 + l16)) << 11) + qa];
                o[dt][r] += pd * (float)__builtin_bit_cast(__bf16, uv);
            }
        }
    }

    #pragma unroll
    for (int r = 0; r < 4; ++r) {
        const float inv = 1.f / den[r];
        const int qa = q0w + quad * 4 + r;
        float* orow = out + ((long)(bh * S_ + qa)) * D_;
        #pragma unroll
        for (int dt = 0; dt < 5; ++dt) {
            const int dim = dt * 16 + l16;
            if (dim < D_) orow[dim] = o[dt][r] * inv;
        }
    }
}

extern "C" void kernel_launch(void* const* d_in, const int* in_sizes, int n_in,
                              void* d_out, int out_size, void* d_ws, size_t ws_size,
                              hipStream_t stream) {
    const float* q        = (const float*)d_in[0];
    const float* k        = (const float*)d_in[1];
    const float* v        = (const float*)d_in[2];
    const float* pos      = (const float*)d_in[3];
    const float* pos_orig = (const float*)d_in[4];
    const float* time_    = (const float*)d_in[5];
    const float* freqs    = (const float*)d_in[6];
    const float* t_freqs  = (const float*)d_in[7];
    const float* scale    = (const float*)d_in[8];
    float* out = (float*)d_out;

    unsigned* qn = (unsigned*)d_ws;                                   // 12.6 MB
    unsigned* kn = qn + (size_t)B_ * H_ * S_ * 48;                    // 12.6 MB
    unsigned short* vt = (unsigned short*)(kn + (size_t)B_ * H_ * S_ * 48);  // 10.5 MB

    pre_kernel<<<dim3(NPREP2 + NVT), dim3(256), 0, stream>>>(
        q, k, v, pos, pos_orig, time_, freqs, t_freqs, scale, qn, kn, vt, out);
    attn_kernel<<<dim3(NQ / 64, B_ * H_), dim3(256), 0, stream>>>(
        (const unsigned short*)qn, (const unsigned short*)kn, vt, out);
}

// Round 11
// 178.334 us; speedup vs baseline: 1.2585x; 1.2585x over previous
//
#include <hip/hip_runtime.h>
#include <math.h>

#define B_ 2
#define H_ 16
#define S_ 2048
#define D_ 72
#define LP 576
#define WEND 1088
#define DP 96        // padded D for qn/kn (3 chunks of 32)
#define DV 80        // padded dims for Vt (5 tiles of 16)
#define NQ (S_ - LP) // 1472 valid q rows

// attn LDS (words): P round-trip [4 waves][16 rows][40 bf16] = 1280 w;
// combine: cb [4][64][21] = 5376 w, db [4][64] = 256 w, PsD [4][16] = 64 w
#define CBW 5376
#define LDSW (CBW + 256 + 64)   // 5696 words = 22784 B

#define NPREP2 (B_ * H_ * S_ / 8)   // 8192 blocks, 8 rows each (2 rows/wave)
#define NVT    (32 * B_ * H_)       // 1024 blocks

typedef __bf16 bf16x8 __attribute__((ext_vector_type(8)));
typedef float f32x4 __attribute__((ext_vector_type(4)));

static __device__ __forceinline__ unsigned pack2bf(float a, float b) {
    __bf16 x = (__bf16)a, y = (__bf16)b;
    unsigned short ux = __builtin_bit_cast(unsigned short, x);
    unsigned short uy = __builtin_bit_cast(unsigned short, y);
    return (unsigned)ux | ((unsigned)uy << 16);
}

static __device__ __forceinline__ f32x4 mfma16(bf16x8 a, bf16x8 b, f32x4 c) {
    return __builtin_amdgcn_mfma_f32_16x16x32_bf16(a, b, c, 0, 0, 0);
}

// ---------- fused pre: prep (2 rows/wave, LDS-repacked uint4 stores) | vtrans (+zero) ----------
__global__ __launch_bounds__(256) void pre_kernel(
    const float* __restrict__ q, const float* __restrict__ k,
    const float* __restrict__ v,
    const float* __restrict__ pos, const float* __restrict__ pos_orig,
    const float* __restrict__ time_, const float* __restrict__ freqs,
    const float* __restrict__ t_freqs, const float* __restrict__ scale,
    unsigned* __restrict__ qn, unsigned* __restrict__ kn,
    unsigned short* __restrict__ vt, float* __restrict__ out)
{
    __shared__ __align__(16) float tile[64 * 77];  // vtrans; aliased by prep repack
    if (blockIdx.x < NPREP2) {
        unsigned short* shp = (unsigned short*)tile;  // [2][8][96] ushorts
        const int wave = threadIdx.x >> 6;
        const int lane = threadIdx.x & 63;
        const int j = lane & 31;               // lane within row
        const int rw = wave * 2 + (lane >> 5); // row within block (0..7)
        const int row = blockIdx.x * 8 + rw;
        const int s = row & (S_ - 1);
        const int h = (row >> 11) & (H_ - 1);
        const int b = row >> 15;
        const long base = (long)row * D_;
        const int p2 = (b * S_ + s) * 2;

        float oq1 = 0.f, oq2 = 0.f, ok1 = 0.f, ok2 = 0.f;
        float pq[6], pk[6];
        float ssq = 0.f, ssk = 0.f;
        if (j < 30) {
            const float x1q = q[base + j], x2q = q[base + j + 30];
            const float x1k = k[base + j], x2k = k[base + j + 30];
            const int g = j / 6, i = j - 6 * g;
            const float fh = freqs[96 + h * 6 + i];
            const float fw = freqs[h * 6 + i];
            const float ft = t_freqs[h * 6 + i];
            const float f  = (g < 2) ? fh : ((g < 4) ? fw : ft);
            const float by_o = pos_orig[p2 + 1] * 2.f - 1.f;
            const float by_p = pos[p2 + 1]      * 2.f - 1.f;
            const float bx_o = pos_orig[p2 + 0] * 2.f - 1.f;
            const float bx_p = pos[p2 + 0]      * 2.f - 1.f;
            const float bt   = time_[b * S_ + s];
            const float bv = (g == 0) ? by_o : (g == 1) ? by_p :
                             (g == 2) ? bx_o : (g == 3) ? bx_p : bt;
            float sn, cs;
            __sincosf(bv * f, &sn, &cs);
            oq1 = x1q * cs - x2q * sn;  oq2 = x2q * cs + x1q * sn;
            ok1 = x1k * cs - x2k * sn;  ok2 = x2k * cs + x1k * sn;
            ssq = oq1 * oq1 + oq2 * oq2;
            ssk = ok1 * ok1 + ok2 * ok2;
        } else {
            const int e0 = 60 + 6 * (j - 30);
            #pragma unroll
            for (int m = 0; m < 3; ++m) {
                const float2 a = *(const float2*)(q + base + e0 + 2 * m);
                const float2 c = *(const float2*)(k + base + e0 + 2 * m);
                pq[2 * m] = a.x; pq[2 * m + 1] = a.y;
                pk[2 * m] = c.x; pk[2 * m + 1] = c.y;
                ssq += a.x * a.x + a.y * a.y;
                ssk += c.x * c.x + c.y * c.y;
            }
        }
        #pragma unroll
        for (int m = 1; m < 32; m <<= 1) { ssq += __shfl_xor(ssq, m); ssk += __shfl_xor(ssk, m); }
        const float ss = sqrtf(scale[h]);
        const float fq = ss * rsqrtf(ssq + 1e-6f);
        const float fk = ss * rsqrtf(ssk + 1e-6f);

        unsigned short* sq_ = shp + rw * 96;          // [8][96] q
        unsigned short* sk_ = shp + 768 + rw * 96;    // k
        if (j < 30) {
            sq_[j]      = __builtin_bit_cast(unsigned short, (__bf16)(oq1 * fq));
            sq_[j + 30] = __builtin_bit_cast(unsigned short, (__bf16)(oq2 * fq));
            sk_[j]      = __builtin_bit_cast(unsigned short, (__bf16)(ok1 * fk));
            sk_[j + 30] = __builtin_bit_cast(unsigned short, (__bf16)(ok2 * fk));
        } else {
            const int e0 = 60 + 6 * (j - 30);
            #pragma unroll
            for (int m = 0; m < 6; ++m) {
                sq_[e0 + m] = __builtin_bit_cast(unsigned short, (__bf16)(pq[m] * fq));
                sk_[e0 + m] = __builtin_bit_cast(unsigned short, (__bf16)(pk[m] * fk));
            }
        }
        __syncthreads();
        // repack: 2 arrays x 8 rows x 12 uint4 = 192 coalesced stores
        const int t = threadIdx.x;
        if (t < 192) {
            const int arr = t / 96, rem = t - arr * 96;
            const int rr = rem / 12, seg = rem - rr * 12;
            uint4 val = make_uint4(0u, 0u, 0u, 0u);
            if (seg < 9) val = ((const uint4*)(shp + arr * 768 + rr * 96))[seg];
            unsigned* dst = (arr ? kn : qn) + ((long)(blockIdx.x * 8 + rr)) * 48;
            ((uint4*)dst)[seg] = val;
        }
    } else {
        // ---- vtrans (+ zero of out rows < LP) ----
        const int bx2 = blockIdx.x - NPREP2;
        const int st = bx2 & 31, bh = bx2 >> 5;
        const int s0 = st * 64;
        const int t = threadIdx.x;
        if (st < 9) {
            float4* o4 = (float4*)(out + (long)(bh * S_ + s0) * D_);
            for (int i = t; i < 1152; i += 256) o4[i] = make_float4(0.f, 0.f, 0.f, 0.f);
        }
        for (int i = t; i < 1152; i += 256) {
            const int r = i / 18, c = i - r * 18;
            const float4 g = ((const float4*)v)[((long)(bh * S_ + s0 + r) * 18) + c];
            float* d = &tile[r * 77 + c * 4];
            d[0] = g.x; d[1] = g.y; d[2] = g.z; d[3] = g.w;
        }
        __syncthreads();
        for (int i = t; i < 1280; i += 256) {
            const int dd = i >> 4, s4 = i & 15;
            float f0 = 0.f, f1 = 0.f, f2 = 0.f, f3 = 0.f;
            if (dd < D_) {
                f0 = tile[(s4 * 4 + 0) * 77 + dd];
                f1 = tile[(s4 * 4 + 1) * 77 + dd];
                f2 = tile[(s4 * 4 + 2) * 77 + dd];
                f3 = tile[(s4 * 4 + 3) * 77 + dd];
            }
            uint2 o; o.x = pack2bf(f0, f1); o.y = pack2bf(f2, f3);
            ((uint2*)vt)[((((long)bh * DV + dd) << 11) + s0 + s4 * 4) >> 2] = o;
        }
    }
}

// ---------- attention: barrier-free main loop; wave-owned 32-key slices ----------
// Block = 64 q-rows, 4 waves. Per 128-key tile, wave w owns keys [kt*128+32w, +32):
// K/V fragments loaded DIRECTLY from global (full-line gathers), P via tiny per-wave
// LDS round-trip. Partial (o, den) combined across waves once at the end.
__global__ __launch_bounds__(256) void attn_kernel(
    const unsigned short* __restrict__ qn, const unsigned short* __restrict__ kn,
    const unsigned short* __restrict__ vt, float* __restrict__ out)
{
    __shared__ __align__(16) unsigned lds[LDSW];
    const int bh = blockIdx.y;
    const int q0 = LP + blockIdx.x * 64;
    const int tid = threadIdx.x;
    const int w = tid >> 6, lane = tid & 63;
    const int quad = lane >> 4, l16 = lane & 15;
    const bool causal = (q0 < WEND);
    const int ntiles = causal ? ((q0 + 191) >> 7) : 9;   // 128-key tiles

    const unsigned short* qn_b = qn + (((long)bh) << 11) * DP;
    const unsigned short* kn_b = kn + (((long)bh) << 11) * DP;
    const unsigned short* vt_b = vt + (long)bh * DV * S_;

    // Q A-frags for all 4 m-groups (rows q0+16m+l16)
    bf16x8 qf[4][3];
    #pragma unroll
    for (int m = 0; m < 4; ++m)
        #pragma unroll
        for (int c = 0; c < 3; ++c)
            qf[m][c] = *(const bf16x8*)(qn_b + (long)(q0 + 16 * m + l16) * DP + c * 32 + quad * 8);

    f32x4 o[4][5];
    float den[4][4];
    #pragma unroll
    for (int m = 0; m < 4; ++m) {
        #pragma unroll
        for (int dt = 0; dt < 5; ++dt) { o[m][dt][0]=0.f; o[m][dt][1]=0.f; o[m][dt][2]=0.f; o[m][dt][3]=0.f; }
        #pragma unroll
        for (int r = 0; r < 4; ++r) den[m][r] = 0.f;
    }

    unsigned short* Pw = (unsigned short*)lds + w * 640;  // [16 rows][40 bf16]

    for (int kt = 0; kt < ntiles; ++kt) {
        const int kb = kt * 128 + 32 * w;   // this wave's 32 keys
        // K frags: 2 key-groups x 3 chunks; V frags: 5 dim-tiles  (direct global)
        bf16x8 kf[2][3], vf[5];
        #pragma unroll
        for (int g = 0; g < 2; ++g)
            #pragma unroll
            for (int c = 0; c < 3; ++c)
                kf[g][c] = *(const bf16x8*)(kn_b + (long)(kb + 16 * g + l16) * DP + c * 32 + quad * 8);
        #pragma unroll
        for (int dt = 0; dt < 5; ++dt)
            vf[dt] = *(const bf16x8*)(vt_b + (((long)(dt * 16 + l16)) << 11) + kb + quad * 8);

        #pragma unroll
        for (int m = 0; m < 4; ++m) {
            f32x4 acc0, acc1;
            acc0[0]=0.f; acc0[1]=0.f; acc0[2]=0.f; acc0[3]=0.f;
            acc1[0]=0.f; acc1[1]=0.f; acc1[2]=0.f; acc1[3]=0.f;
            #pragma unroll
            for (int c = 0; c < 3; ++c) {
                acc0 = mfma16(qf[m][c], kf[0][c], acc0);
                acc1 = mfma16(qf[m][c], kf[1][c], acc1);
            }
            // exp + mask + den + P store (C-layout: col=key l16, row=quad*4+r)
            #pragma unroll
            for (int g = 0; g < 2; ++g) {
                const int ka = kb + 16 * g + l16;
                #pragma unroll
                for (int r = 0; r < 4; ++r) {
                    const int qa = q0 + 16 * m + quad * 4 + r;
                    float p = g ? acc1[r] : acc0[r];
                    const bool valid = causal ? (ka <= qa) : (ka < WEND);
                    p = valid ? __expf(p) : 0.f;
                    const __bf16 pb = (__bf16)p;
                    den[m][r] += (float)pb;
                    Pw[(quad * 4 + r) * 40 + 16 * g + l16] = __builtin_bit_cast(unsigned short, pb);
                }
            }
            // P round-trip C->A (same-wave LDS ordering), then PV
            const bf16x8 pa = *(const bf16x8*)(Pw + l16 * 40 + quad * 8);
            #pragma unroll
            for (int dt = 0; dt < 5; ++dt)
                o[m][dt] = mfma16(pa, vf[dt], o[m][dt]);
        }
    }

    // reduce den over key-lanes (l16) within wave
    #pragma unroll
    for (int m = 0; m < 4; ++m)
        #pragma unroll
        for (int r = 0; r < 4; ++r)
            #pragma unroll
            for (int x = 1; x < 16; x <<= 1) den[m][r] += __shfl_xor(den[m][r], x);

    // ---- cross-wave combine (keys were split across waves) ----
    __syncthreads();                       // all waves done with P region (aliased below)
    float* cb  = (float*)lds;              // [4][64][21]
    float* db  = (float*)lds + CBW;        // [4][64]
    float* PsD = (float*)lds + CBW + 256;  // [4][16]
    if (l16 == 0)
        #pragma unroll
        for (int m = 0; m < 4; ++m)
            #pragma unroll
            for (int r = 0; r < 4; ++r)
                db[w * 64 + 16 * m + quad * 4 + r] = den[m][r];

    float ofin[5][4];
    #pragma unroll
    for (int dt = 0; dt < 5; ++dt) {
        __syncthreads();
        #pragma unroll
        for (int m = 0; m < 4; ++m)
            #pragma unroll
            for (int r = 0; r < 4; ++r)
                cb[w * 1344 + (16 * m + quad * 4 + r) * 21 + l16] = o[m][dt][r];
        __syncthreads();
        #pragma unroll
        for (int r = 0; r < 4; ++r) {
            const int row = 16 * w + quad * 4 + r;
            ofin[dt][r] = cb[row * 21 + l16] + cb[1344 + row * 21 + l16]
                        + cb[2688 + row * 21 + l16] + cb[4032 + row * 21 + l16];
        }
    }
    float dfin[4];
    #pragma unroll
    for (int r = 0; r < 4; ++r) {
        const int row = 16 * w + quad * 4 + r;
        dfin[r] = db[row] + db[64 + row] + db[128 + row] + db[192 + row];
    }

    if (!causal) {  // diagonal self-key k == q (window rows); wave w owns rows 16w..
        bf16x8 qw[3];
        #pragma unroll
        for (int m = 0; m < 4; ++m)
            if (w == m) { qw[0] = qf[m][0]; qw[1] = qf[m][1]; qw[2] = qf[m][2]; }
        float sp = 0.f;
        #pragma unroll
        for (int c = 0; c < 3; ++c) {
            const bf16x8 kd = *(const bf16x8*)(kn_b + (long)(q0 + 16 * w + l16) * DP + c * 32 + quad * 8);
            #pragma unroll
            for (int j = 0; j < 8; ++j) sp += (float)qw[c][j] * (float)kd[j];
        }
        sp += __shfl_xor(sp, 16);
        sp += __shfl_xor(sp, 32);
        if (quad == 0) PsD[w * 16 + l16] = __expf(sp);
        #pragma unroll
        for (int r = 0; r < 4; ++r) {
            const float pd = PsD[w * 16 + quad * 4 + r];
            dfin[r] += pd;
            const int qa = q0 + 16 * w + quad * 4 + r;
            #pragma unroll
            for (int dt = 0; dt < 5; ++dt) {
                const unsigned short uv = vt_b[(((long)(dt * 16 + l16)) << 11) + qa];
                ofin[dt][r] += pd * (float)__builtin_bit_cast(__bf16, uv);
            }
        }
    }

    #pragma unroll
    for (int r = 0; r < 4; ++r) {
        const float inv = 1.f / dfin[r];
        const int qa = q0 + 16 * w + quad * 4 + r;
        float* orow = out + ((long)(bh * S_ + qa)) * D_;
        #pragma unroll
        for (int dt = 0; dt < 5; ++dt) {
            const int dim = dt * 16 + l16;
            if (dim < D_) orow[dim] = ofin[dt][r] * inv;
        }
    }
}

extern "C" void kernel_launch(void* const* d_in, const int* in_sizes, int n_in,
                              void* d_out, int out_size, void* d_ws, size_t ws_size,
                              hipStream_t stream) {
    const float* q        = (const float*)d_in[0];
    const float* k        = (const float*)d_in[1];
    const float* v        = (const float*)d_in[2];
    const float* pos      = (const float*)d_in[3];
    const float* pos_orig = (const float*)d_in[4];
    const float* time_    = (const float*)d_in[5];
    const float* freqs    = (const float*)d_in[6];
    const float* t_freqs  = (const float*)d_in[7];
    const float* scale    = (const float*)d_in[8];
    float* out = (float*)d_out;

    unsigned* qn = (unsigned*)d_ws;                                   // 12.6 MB
    unsigned* kn = qn + (size_t)B_ * H_ * S_ * 48;                    // 12.6 MB
    unsigned short* vt = (unsigned short*)(kn + (size_t)B_ * H_ * S_ * 48);  // 10.5 MB

    pre_kernel<<<dim3(NPREP2 + NVT), dim3(256), 0, stream>>>(
        q, k, v, pos, pos_orig, time_, freqs, t_freqs, scale, qn, kn, vt, out);
    attn_kernel<<<dim3(NQ / 64, B_ * H_), dim3(256), 0, stream>>>(
        (const unsigned short*)qn, (const unsigned short*)kn, vt, out);
}